// Round 1
// baseline (506.990 us; speedup 1.0000x reference)
//
#include <hip/hip_runtime.h>
#include <hip/hip_bf16.h>
#include <stdint.h>

typedef short bf16x8 __attribute__((ext_vector_type(8)));
typedef float f32x16 __attribute__((ext_vector_type(16)));

#define T 2048
#define KLEN 2049
#define DK 32
#define NCO 32
#define NCI 32
#define NB 32

#define GR 2136          // padded reversed row length
#define SREF 2055        // x[s] lives at g = SREF - s
#define WT_CH 257        // 8-wide d-chunks, d in [0,2056)
#define WT_ELEMS (NCI*WT_CH*NCO*8)
#define XR_ELEMS (NB*NCI*GR)

#define WT_OFF 0
#define XR_OFF (WT_ELEMS*2)
#define XRS_OFF (XR_OFF + XR_ELEMS*2)

#define CA 0
#define CB 8704

// ---------------- kernel-generation: SIREN -> flipped, fragment-layout W ----
__global__ __launch_bounds__(256) void gen_w(
    const float* __restrict__ rel_pos,
    const float* __restrict__ w1, const float* __restrict__ b1, const float* __restrict__ om1,
    const float* __restrict__ w2, const float* __restrict__ b2, const float* __restrict__ om2,
    const float* __restrict__ w3, const float* __restrict__ b3,
    uint16_t* __restrict__ Wt)
{
    int d = blockIdx.x;          // flipped lag, 0..2055
    int tid = threadIdx.x;
    if (d >= KLEN) {             // zero pad region
        for (int r = 0; r < 4; ++r) {
            int coci = tid + 256*r;
            int co = coci >> 5, ci = coci & 31;
            Wt[(((ci*WT_CH + (d>>3))*NCO + co)<<3) + (d&7)] = 0;
        }
        return;
    }
    int kk = 2048 - d;
    float pos = rel_pos[kk];
    __shared__ float h1[DK];
    __shared__ float h2[DK];
    if (tid < DK) h1[tid] = sinf(om1[0]*(w1[tid]*pos + b1[tid]));
    __syncthreads();
    if (tid < DK) {
        float a = b2[tid];
        for (int j = 0; j < DK; ++j) a += w2[tid*DK+j]*h1[j];
        h2[tid] = sinf(om2[0]*a);
    }
    __syncthreads();
    for (int r = 0; r < 4; ++r) {
        int coci = tid + 256*r;
        float a = b3[coci];
        for (int j = 0; j < DK; ++j) a += w3[coci*DK+j]*h2[j];
        int co = coci >> 5, ci = coci & 31;
        __hip_bfloat16 hv = __float2bfloat16(a);
        Wt[(((ci*WT_CH + (d>>3))*NCO + co)<<3) + (d&7)] = *(uint16_t*)&hv;
    }
}

// ---------------- x -> reversed, zero-padded bf16 (plus shifted copy) -------
__global__ __launch_bounds__(256) void gen_x(const float* __restrict__ x,
                                             uint16_t* __restrict__ xr,
                                             uint16_t* __restrict__ xrs)
{
    int idx = blockIdx.x*256 + threadIdx.x;
    if (idx >= NB*NCI*GR) return;
    int row = idx / GR;          // b*32+ci
    int g = idx - row*GR;
    int s = SREF - g;
    float v  = (s  >= 0 && s  < T) ? x[row*T + s]  : 0.f;
    int s2 = s - 1;              // value at g+1
    float v2 = (s2 >= 0 && s2 < T) ? x[row*T + s2] : 0.f;
    __hip_bfloat16 hv = __float2bfloat16(v);
    __hip_bfloat16 hv2 = __float2bfloat16(v2);
    xr[idx]  = *(uint16_t*)&hv;
    xrs[idx] = *(uint16_t*)&hv2;
}

// ---------------- causal conv as implicit-Toeplitz MFMA GEMM ----------------
__global__ __launch_bounds__(256) void conv(
    const uint16_t* __restrict__ Wt, const uint16_t* __restrict__ xr,
    const uint16_t* __restrict__ xrs,
    const float* __restrict__ bias, float* __restrict__ out)
{
    __shared__ uint4 lds4[2048];   // 32 KiB: staging (2x 8704B) / reduce (32KB)
    char* lds = (char*)lds4;
    int tid = threadIdx.x;
    int tt = blockIdx.x & 31;
    int b  = blockIdx.x >> 5;
    int t0 = tt << 6;
    int w = tid >> 6, lane = tid & 63, n = lane & 31, hi = lane >> 5;

    f32x16 acc[2];
    #pragma unroll
    for (int r = 0; r < 16; ++r) { acc[0][r] = 0.f; acc[1][r] = 0.f; }

    int nw = tt + 1;               // d in [0, t0+64)
    for (int wi = 0; wi < nw; ++wi) {
        int d0 = wi << 6;
        int g0 = 1992 - t0 + d0;   // SREF - (t0+63) + d0, multiple of 8
        // stage: 32ci x 136 slots, two parity copies, 16B granules
        for (int gi = tid; gi < 1088; gi += 256) {
            int cpy = gi >= 544;
            int gg = cpy ? gi - 544 : gi;
            int ci = gg / 17;
            int q8 = (gg - ci*17) << 3;
            const uint16_t* src = (cpy ? xrs : xr) + ((b*NCI + ci)*GR + g0 + q8);
            char* dst = lds + (cpy ? CB : CA) + ci*272 + (q8<<1);
            *(uint4*)dst = *(const uint4*)src;
        }
        __syncthreads();
        for (int c = 0; c < 4; ++c) {
            int dc = (d0 >> 3) + (c << 1);
            #pragma unroll
            for (int cii = 0; cii < 8; ++cii) {
                int ci = (cii<<2) + w;          // wave-private ci subset
                bf16x8 av = *(const bf16x8*)(Wt + (((ci*WT_CH + dc + hi)*NCO + n)<<3));
                #pragma unroll
                for (int tile = 0; tile < 2; ++tile) {
                    int start = 63 - (tile<<5) - n + (c<<4) + (hi<<3);
                    int base = (start & 1) ? (CB - 2) : CA;
                    int addr = base + ci*272 + (start<<1);
                    union { uint32_t u[4]; bf16x8 v; } bb;
                    bb.u[0] = *(const uint32_t*)(lds + addr);
                    bb.u[1] = *(const uint32_t*)(lds + addr + 4);
                    bb.u[2] = *(const uint32_t*)(lds + addr + 8);
                    bb.u[3] = *(const uint32_t*)(lds + addr + 12);
                    acc[tile] = __builtin_amdgcn_mfma_f32_32x32x16_bf16(av, bb.v, acc[tile], 0, 0, 0);
                }
            }
        }
        __syncthreads();
    }
    // cross-wave ci reduction via LDS
    float* red = (float*)lds;
    #pragma unroll
    for (int tile = 0; tile < 2; ++tile)
        #pragma unroll
        for (int r = 0; r < 16; ++r)
            red[((w*2 + tile)*16 + r)*64 + lane] = acc[tile][r];
    __syncthreads();
    for (int e = tid; e < 2048; e += 256) {
        int lane_e = e & 63;
        int reg = (e >> 6) & 15;
        int tile = e >> 10;
        float s = 0.f;
        #pragma unroll
        for (int ww = 0; ww < 4; ++ww) s += red[((ww*2 + tile)*16 + reg)*64 + lane_e];
        int co = (reg & 3) + ((reg >> 2) << 3) + ((lane_e >> 5) << 2);
        int t = t0 + (tile << 5) + (lane_e & 31);
        out[(b*NCO + co)*T + t] = s + bias[co];
    }
}

extern "C" void kernel_launch(void* const* d_in, const int* in_sizes, int n_in,
                              void* d_out, int out_size, void* d_ws, size_t ws_size,
                              hipStream_t stream)
{
    const float* x       = (const float*)d_in[0];
    const float* rel_pos = (const float*)d_in[1];
    const float* w1  = (const float*)d_in[2];
    const float* b1  = (const float*)d_in[3];
    const float* om1 = (const float*)d_in[4];
    const float* w2  = (const float*)d_in[5];
    const float* b2  = (const float*)d_in[6];
    const float* om2 = (const float*)d_in[7];
    const float* w3  = (const float*)d_in[8];
    const float* b3  = (const float*)d_in[9];
    const float* bias = (const float*)d_in[10];
    float* out = (float*)d_out;
    char* ws = (char*)d_ws;
    uint16_t* Wt  = (uint16_t*)(ws + WT_OFF);
    uint16_t* xrp = (uint16_t*)(ws + XR_OFF);
    uint16_t* xrs = (uint16_t*)(ws + XRS_OFF);

    hipLaunchKernelGGL(gen_w, dim3(WT_CH*8), dim3(256), 0, stream,
                       rel_pos, w1, b1, om1, w2, b2, om2, w3, b3, Wt);
    int n2 = NB*NCI*GR;
    hipLaunchKernelGGL(gen_x, dim3((n2+255)/256), dim3(256), 0, stream, x, xrp, xrs);
    hipLaunchKernelGGL(conv, dim3(NB*32), dim3(256), 0, stream, Wt, xrp, xrs, bias, out);
}

// Round 2
// 383.447 us; speedup vs baseline: 1.3222x; 1.3222x over previous
//
#include <hip/hip_runtime.h>
#include <hip/hip_bf16.h>
#include <stdint.h>

typedef short bf16x8 __attribute__((ext_vector_type(8)));
typedef float f32x16 __attribute__((ext_vector_type(16)));

#define T 2048
#define KLEN 2049
#define DK 32
#define NCO 32
#define NCI 32
#define NB 32

#define GR 2120          // padded reversed row length
#define SREF 2055        // x[s] lives at g = SREF - s  (xr); xrs holds value at g+1
#define WT_CH 257        // 8-wide d-chunks, d in [0,2056)
#define WT_ELEMS (NCI*WT_CH*NCO*8)
#define XR_ELEMS (NB*NCI*GR)

#define WT_OFF 0
#define XR_OFF (WT_ELEMS*2)
#define XRS_OFF (XR_OFF + XR_ELEMS*2)

#define SLOT 104         // staged elements per ci per parity copy
#define CIB 208          // bytes per ci row (13 x 16B granules)
#define CPYB (NCI*CIB)   // 6656 per parity copy
#define TILEB (2*CPYB)   // 13312 per tile buffer

// ---------------- kernel-generation: SIREN -> flipped, fragment-layout W ----
__global__ __launch_bounds__(256) void gen_w(
    const float* __restrict__ rel_pos,
    const float* __restrict__ w1, const float* __restrict__ b1, const float* __restrict__ om1,
    const float* __restrict__ w2, const float* __restrict__ b2, const float* __restrict__ om2,
    const float* __restrict__ w3, const float* __restrict__ b3,
    uint16_t* __restrict__ Wt)
{
    int d = blockIdx.x;          // flipped lag, 0..2055
    int tid = threadIdx.x;
    if (d >= KLEN) {             // zero pad region
        for (int r = 0; r < 4; ++r) {
            int coci = tid + 256*r;
            int co = coci >> 5, ci = coci & 31;
            Wt[(((ci*WT_CH + (d>>3))*NCO + co)<<3) + (d&7)] = 0;
        }
        return;
    }
    int kk = 2048 - d;
    float pos = rel_pos[kk];
    __shared__ float h1[DK];
    __shared__ float h2[DK];
    if (tid < DK) h1[tid] = sinf(om1[0]*(w1[tid]*pos + b1[tid]));
    __syncthreads();
    if (tid < DK) {
        float a = b2[tid];
        for (int j = 0; j < DK; ++j) a += w2[tid*DK+j]*h1[j];
        h2[tid] = sinf(om2[0]*a);
    }
    __syncthreads();
    for (int r = 0; r < 4; ++r) {
        int coci = tid + 256*r;
        float a = b3[coci];
        for (int j = 0; j < DK; ++j) a += w3[coci*DK+j]*h2[j];
        int co = coci >> 5, ci = coci & 31;
        __hip_bfloat16 hv = __float2bfloat16(a);
        Wt[(((ci*WT_CH + (d>>3))*NCO + co)<<3) + (d&7)] = *(uint16_t*)&hv;
    }
}

// ---------------- x -> reversed, zero-padded bf16 (plus shifted copy) -------
__global__ __launch_bounds__(256) void gen_x(const float* __restrict__ x,
                                             uint16_t* __restrict__ xr,
                                             uint16_t* __restrict__ xrs)
{
    int idx = blockIdx.x*256 + threadIdx.x;
    if (idx >= NB*NCI*GR) return;
    int row = idx / GR;          // b*32+ci
    int g = idx - row*GR;
    int s = SREF - g;
    float v  = (s  >= 0 && s  < T) ? x[row*T + s]  : 0.f;
    int s2 = s - 1;              // value at g+1
    float v2 = (s2 >= 0 && s2 < T) ? x[row*T + s2] : 0.f;
    __hip_bfloat16 hv = __float2bfloat16(v);
    __hip_bfloat16 hv2 = __float2bfloat16(v2);
    xr[idx]  = *(uint16_t*)&hv;
    xrs[idx] = *(uint16_t*)&hv2;
}

// ---------------- causal conv as implicit-Toeplitz MFMA GEMM ----------------
// Block = (b, pair pr): tile A = t-tile (63-pr), tile B = t-tile pr (32 t's each).
// Uniform 33 window-tiles per block. 4 waves split ci 4-way.
__global__ __launch_bounds__(256, 4) void conv(
    const uint16_t* __restrict__ Wt, const uint16_t* __restrict__ xr,
    const uint16_t* __restrict__ xrs,
    const float* __restrict__ bias, float* __restrict__ out)
{
    __shared__ uint4 lds4[2*TILEB/16];   // 26624 B (also >= 16KB reduce area)
    char* lds = (char*)lds4;
    int tid = threadIdx.x;
    int pr = blockIdx.x & 31;
    int b  = blockIdx.x >> 5;
    int ttB = pr, ttA = 63 - pr;
    int t0A = ttA << 5, t0B = ttB << 5;
    int nwA = ((63 - pr) >> 1) + 1;
    int nwB = (pr >> 1) + 1;
    int w = tid >> 6, lane = tid & 63, n = lane & 31, hi = lane >> 5;

    f32x16 acc0, acc1;
    #pragma unroll
    for (int r = 0; r < 16; ++r) { acc0[r] = 0.f; acc1[r] = 0.f; }

    const int rowb = b * NCI;

    for (int wi = 0; wi < nwA; ++wi) {
        int actB = (wi < nwB);
        int g0A = 2016 - t0A + (wi << 6);   // multiple of 8
        int g0B = 2016 - t0B + (wi << 6);
        // stage: per tile, 2 parity copies x 32 ci x 13 16B-granules = 832
        int ng = actB ? 1664 : 832;
        for (int gi = tid; gi < ng; gi += 256) {
            int tb = gi >= 832;
            int g2 = gi - (tb << 9) - (tb << 8) - (tb << 6);  // gi - 832*tb
            int cpy = g2 >= 416;
            int g3 = g2 - (cpy ? 416 : 0);
            int ci = g3 / 13;
            int q  = g3 - ci*13;
            int g0 = tb ? g0B : g0A;
            const uint16_t* src = (cpy ? xrs : xr) + ((rowb + ci)*GR + g0 + (q<<3));
            char* dst = lds + tb*TILEB + cpy*CPYB + ci*CIB + (q<<4);
            *(uint4*)dst = *(const uint4*)src;
        }
        __syncthreads();
        int dcw = (wi << 3);
        for (int c = 0; c < 4; ++c) {
            int o = 39 - n + (c << 4) + (hi << 3);
            int par = o & 1;
            int boff = par*CPYB + ((o - par) << 1);
            int dc = dcw + (c << 1) + hi;
            #pragma unroll
            for (int cii = 0; cii < 8; ++cii) {
                int ci = (cii << 2) + w;          // wave-private ci subset
                bf16x8 av = *(const bf16x8*)(Wt + (((ci*WT_CH + dc)*NCO + n) << 3));
                {
                    const char* p = lds + ci*CIB + boff;
                    union { uint32_t u[4]; bf16x8 v; } bb;
                    bb.u[0] = *(const uint32_t*)(p);
                    bb.u[1] = *(const uint32_t*)(p + 4);
                    bb.u[2] = *(const uint32_t*)(p + 8);
                    bb.u[3] = *(const uint32_t*)(p + 12);
                    acc0 = __builtin_amdgcn_mfma_f32_32x32x16_bf16(av, bb.v, acc0, 0, 0, 0);
                }
                if (actB) {
                    const char* p = lds + TILEB + ci*CIB + boff;
                    union { uint32_t u[4]; bf16x8 v; } bb;
                    bb.u[0] = *(const uint32_t*)(p);
                    bb.u[1] = *(const uint32_t*)(p + 4);
                    bb.u[2] = *(const uint32_t*)(p + 8);
                    bb.u[3] = *(const uint32_t*)(p + 12);
                    acc1 = __builtin_amdgcn_mfma_f32_32x32x16_bf16(av, bb.v, acc1, 0, 0, 0);
                }
            }
        }
        __syncthreads();
    }

    // cross-wave ci reduction via LDS, one tile at a time (16 KB area)
    float* red = (float*)lds4;
    // ---- tile A ----
    #pragma unroll
    for (int r = 0; r < 16; ++r)
        red[(w*16 + r)*64 + lane] = acc0[r];
    __syncthreads();
    for (int e = tid; e < 1024; e += 256) {
        int lane_e = e & 63;
        int reg = e >> 6;
        float s = 0.f;
        #pragma unroll
        for (int ww = 0; ww < 4; ++ww) s += red[(ww*16 + reg)*64 + lane_e];
        int co = (reg & 3) + ((reg >> 2) << 3) + ((lane_e >> 5) << 2);
        int t = t0A + (lane_e & 31);
        out[(b*NCO + co)*T + t] = s + bias[co];
    }
    __syncthreads();
    // ---- tile B ----
    #pragma unroll
    for (int r = 0; r < 16; ++r)
        red[(w*16 + r)*64 + lane] = acc1[r];
    __syncthreads();
    for (int e = tid; e < 1024; e += 256) {
        int lane_e = e & 63;
        int reg = e >> 6;
        float s = 0.f;
        #pragma unroll
        for (int ww = 0; ww < 4; ++ww) s += red[(ww*16 + reg)*64 + lane_e];
        int co = (reg & 3) + ((reg >> 2) << 3) + ((lane_e >> 5) << 2);
        int t = t0B + (lane_e & 31);
        out[(b*NCO + co)*T + t] = s + bias[co];
    }
}

extern "C" void kernel_launch(void* const* d_in, const int* in_sizes, int n_in,
                              void* d_out, int out_size, void* d_ws, size_t ws_size,
                              hipStream_t stream)
{
    const float* x       = (const float*)d_in[0];
    const float* rel_pos = (const float*)d_in[1];
    const float* w1  = (const float*)d_in[2];
    const float* b1  = (const float*)d_in[3];
    const float* om1 = (const float*)d_in[4];
    const float* w2  = (const float*)d_in[5];
    const float* b2  = (const float*)d_in[6];
    const float* om2 = (const float*)d_in[7];
    const float* w3  = (const float*)d_in[8];
    const float* b3  = (const float*)d_in[9];
    const float* bias = (const float*)d_in[10];
    float* out = (float*)d_out;
    char* ws = (char*)d_ws;
    uint16_t* Wt  = (uint16_t*)(ws + WT_OFF);
    uint16_t* xrp = (uint16_t*)(ws + XR_OFF);
    uint16_t* xrs = (uint16_t*)(ws + XRS_OFF);

    hipLaunchKernelGGL(gen_w, dim3(WT_CH*8), dim3(256), 0, stream,
                       rel_pos, w1, b1, om1, w2, b2, om2, w3, b3, Wt);
    int n2 = NB*NCI*GR;
    hipLaunchKernelGGL(gen_x, dim3((n2+255)/256), dim3(256), 0, stream, x, xrp, xrs);
    hipLaunchKernelGGL(conv, dim3(NB*32), dim3(256), 0, stream, Wt, xrp, xrs, bias, out);
}